// Round 5
// baseline (4667.849 us; speedup 1.0000x reference)
//
#include <hip/hip_runtime.h>

#define HID 128
#define BN_EPS 1e-5f
#define NBSHIFT 7
#define BWIDTH 128

typedef __bf16 bf16;
typedef __attribute__((ext_vector_type(8))) __bf16 bf16x8;
typedef __attribute__((ext_vector_type(4))) float f32x4;

__device__ __forceinline__ float bnrelu(float x, float a, float c) {
  return fmaxf(fmaf(a, x, c), 0.f);
}

// ---------------- bucket histogram ----------------
__global__ __launch_bounds__(256)
void histB_k(const int* __restrict__ dst, int* __restrict__ bcnt, int E, int NB) {
  __shared__ int h[1024];
  int tid = threadIdx.x;
  for (int i = tid; i < NB; i += 256) h[i] = 0;
  __syncthreads();
  for (int i = blockIdx.x * 256 + tid; i < E; i += gridDim.x * 256)
    atomicAdd(&h[dst[i] >> NBSHIFT], 1);
  __syncthreads();
  for (int i = tid; i < NB; i += 256) if (h[i]) atomicAdd(&bcnt[i], h[i]);
}

// ---------------- bucket exclusive scan (NB <= 1024, one block of 1024) ----------------
__global__ void scanB_k(const int* __restrict__ bcnt, int* __restrict__ boff,
                        int* __restrict__ bcur, int NB) {
  __shared__ int wt[16];
  int tid = threadIdx.x, lane = tid & 63, wv = tid >> 6;
  int v = (tid < NB) ? bcnt[tid] : 0;
  int x = v;
#pragma unroll
  for (int d = 1; d < 64; d <<= 1) { int t = __shfl_up(x, d, 64); if (lane >= d) x += t; }
  if (lane == 63) wt[wv] = x;
  __syncthreads();
  if (wv == 0) {
    int w = (lane < 16) ? wt[lane] : 0;
#pragma unroll
    for (int d = 1; d < 16; d <<= 1) { int t = __shfl_up(w, d, 64); if (lane >= d) w += t; }
    if (lane < 16) wt[lane] = w;
  }
  __syncthreads();
  int excl = (wv ? wt[wv - 1] : 0) + x - v;
  if (tid < NB) { boff[tid] = excl; bcur[tid] = excl; }
  if (tid == NB - 1) boff[NB] = excl + v;
}

// ---------------- edge partition into dst-buckets, packed (dl<<17)|src ----------------
__global__ __launch_bounds__(256)
void part_k(const int* __restrict__ src, const int* __restrict__ dst,
            int* __restrict__ bcur, unsigned* __restrict__ ebuf, int E, int NB) {
  __shared__ int lcnt[1024], gbase[1024], lcur[1024];
  int tid = threadIdx.x;
  for (int i = tid; i < NB; i += 256) { lcnt[i] = 0; lcur[i] = 0; }
  __syncthreads();
  int base = blockIdx.x * 2048;
  int ok[8]; unsigned pk[8]; int bk[8];
#pragma unroll
  for (int u = 0; u < 8; ++u) {
    int e = base + u * 256 + tid;
    if (e < E) {
      int s = src[e], d = dst[e];
      ok[u] = 1; bk[u] = d >> NBSHIFT;
      pk[u] = ((unsigned)(d & (BWIDTH - 1)) << 17) | (unsigned)s;
      atomicAdd(&lcnt[bk[u]], 1);
    } else ok[u] = 0;
  }
  __syncthreads();
  for (int i = tid; i < NB; i += 256) if (lcnt[i]) gbase[i] = atomicAdd(&bcur[i], lcnt[i]);
  __syncthreads();
#pragma unroll
  for (int u = 0; u < 8; ++u) if (ok[u]) {
    int sl = atomicAdd(&lcur[bk[u]], 1);
    ebuf[gbase[bk[u]] + sl] = pk[u];
  }
}

// ---------------- weight convert to bf16 ----------------
__global__ __launch_bounds__(256)
void wconv_k(const float* __restrict__ W0, const float* __restrict__ W1,
             const float* __restrict__ pW1, const float* __restrict__ pW2,
             bf16* __restrict__ Wb) {
  int idx = (blockIdx.x * 256 + threadIdx.x) * 4;
  int seg = idx >> 14, loc = idx & 16383;
  const float* srcp = seg < 3 ? W0 + (size_t)seg * 16384
                    : seg < 6 ? W1 + (size_t)(seg - 3) * 16384
                    : seg == 6 ? pW1 : pW2;
  float4 v = *(const float4*)(srcp + loc);
  union { bf16 h[4]; unsigned long long u; } pk;
  pk.h[0] = (bf16)v.x; pk.h[1] = (bf16)v.y; pk.h[2] = (bf16)v.z; pk.h[3] = (bf16)v.w;
  *(unsigned long long*)(Wb + idx) = pk.u;
}

// ---------------- bucketed edge-centric aggregation ----------------
// MODE 0: gather f32 Hf raw (layer 0).  MODE 1: gather bf16 Hh, apply
// relu(a3*relu(a2*x+c2)+c3). Self term always from f32 Hf (+ transform if MODE).
template<int MODE>
__global__ __launch_bounds__(256)
void aggb_k(const float* __restrict__ Hf, const bf16* __restrict__ Hh,
            const float* __restrict__ ac1, const float* __restrict__ g1, const float* __restrict__ b1,
            const float* __restrict__ ac2, const float* __restrict__ g2, const float* __restrict__ b2,
            float invN,
            const int* __restrict__ boff, const unsigned* __restrict__ ebuf,
            bf16* __restrict__ Z, int Nn) {
  __shared__ float acc[BWIDTH * 128];   // 64KB
  __shared__ int deg[BWIDTH];
  __shared__ float sA2[128], sC2[128], sA3[128], sC3[128];
  int tid = threadIdx.x;
  if (MODE && tid < 128) {
    float mu = ac1[tid] * invN;
    float var = fmaxf(ac1[128 + tid] * invN - mu * mu, 0.f);
    float a = g1[tid] * rsqrtf(var + BN_EPS);
    sA2[tid] = a; sC2[tid] = fmaf(-a, mu, b1[tid]);
    mu = ac2[tid] * invN;
    var = fmaxf(ac2[128 + tid] * invN - mu * mu, 0.f);
    a = g2[tid] * rsqrtf(var + BN_EPS);
    sA3[tid] = a; sC3[tid] = fmaf(-a, mu, b2[tid]);
  }
  for (int i = tid; i < BWIDTH * 128; i += 256) acc[i] = 0.f;
  if (tid < BWIDTH) deg[tid] = 0;
  __syncthreads();
  int wv = tid >> 6, lane = tid & 63;
  int cA = lane, cB = lane + 64;
  float a2A = 0, c2A = 0, a3A = 0, c3A = 0, a2B = 0, c2B = 0, a3B = 0, c3B = 0;
  if (MODE) {
    a2A = sA2[cA]; c2A = sC2[cA]; a3A = sA3[cA]; c3A = sC3[cA];
    a2B = sA2[cB]; c2B = sC2[cB]; a3B = sA3[cB]; c3B = sC3[cB];
  }
  int beg = boff[blockIdx.x], end = boff[blockIdx.x + 1];
  int e = beg + wv;
  while (e + 12 < end) {
    unsigned v0 = ebuf[e], v1 = ebuf[e + 4], v2 = ebuf[e + 8], v3 = ebuf[e + 12];
    int s0 = v0 & 0x1FFFF, s1 = v1 & 0x1FFFF, s2 = v2 & 0x1FFFF, s3 = v3 & 0x1FFFF;
    int d0 = v0 >> 17, d1 = v1 >> 17, d2 = v2 >> 17, d3 = v3 >> 17;
    float x0, y0, x1, y1, x2, y2, x3, y3;
    if (MODE) {
      x0 = (float)Hh[(size_t)s0 * HID + cA]; y0 = (float)Hh[(size_t)s0 * HID + cB];
      x1 = (float)Hh[(size_t)s1 * HID + cA]; y1 = (float)Hh[(size_t)s1 * HID + cB];
      x2 = (float)Hh[(size_t)s2 * HID + cA]; y2 = (float)Hh[(size_t)s2 * HID + cB];
      x3 = (float)Hh[(size_t)s3 * HID + cA]; y3 = (float)Hh[(size_t)s3 * HID + cB];
      x0 = bnrelu(bnrelu(x0, a2A, c2A), a3A, c3A); y0 = bnrelu(bnrelu(y0, a2B, c2B), a3B, c3B);
      x1 = bnrelu(bnrelu(x1, a2A, c2A), a3A, c3A); y1 = bnrelu(bnrelu(y1, a2B, c2B), a3B, c3B);
      x2 = bnrelu(bnrelu(x2, a2A, c2A), a3A, c3A); y2 = bnrelu(bnrelu(y2, a2B, c2B), a3B, c3B);
      x3 = bnrelu(bnrelu(x3, a2A, c2A), a3A, c3A); y3 = bnrelu(bnrelu(y3, a2B, c2B), a3B, c3B);
    } else {
      x0 = Hf[(size_t)s0 * HID + cA]; y0 = Hf[(size_t)s0 * HID + cB];
      x1 = Hf[(size_t)s1 * HID + cA]; y1 = Hf[(size_t)s1 * HID + cB];
      x2 = Hf[(size_t)s2 * HID + cA]; y2 = Hf[(size_t)s2 * HID + cB];
      x3 = Hf[(size_t)s3 * HID + cA]; y3 = Hf[(size_t)s3 * HID + cB];
    }
    atomicAdd(&acc[d0 * 128 + cA], x0); atomicAdd(&acc[d0 * 128 + cB], y0);
    atomicAdd(&acc[d1 * 128 + cA], x1); atomicAdd(&acc[d1 * 128 + cB], y1);
    atomicAdd(&acc[d2 * 128 + cA], x2); atomicAdd(&acc[d2 * 128 + cB], y2);
    atomicAdd(&acc[d3 * 128 + cA], x3); atomicAdd(&acc[d3 * 128 + cB], y3);
    if (lane == 0) {
      atomicAdd(&deg[d0], 1); atomicAdd(&deg[d1], 1);
      atomicAdd(&deg[d2], 1); atomicAdd(&deg[d3], 1);
    }
    e += 16;
  }
  for (; e < end; e += 4) {
    unsigned v = ebuf[e];
    int s = v & 0x1FFFF, d = v >> 17;
    float gx, gy;
    if (MODE) {
      gx = (float)Hh[(size_t)s * HID + cA]; gy = (float)Hh[(size_t)s * HID + cB];
      gx = bnrelu(bnrelu(gx, a2A, c2A), a3A, c3A); gy = bnrelu(bnrelu(gy, a2B, c2B), a3B, c3B);
    } else {
      gx = Hf[(size_t)s * HID + cA]; gy = Hf[(size_t)s * HID + cB];
    }
    atomicAdd(&acc[d * 128 + cA], gx); atomicAdd(&acc[d * 128 + cB], gy);
    if (lane == 0) atomicAdd(&deg[d], 1);
  }
  __syncthreads();
  int nb0 = blockIdx.x * BWIDTH;
  for (int i = wv; i < BWIDTH; i += 4) {
    int n = nb0 + i;
    if (n >= Nn) break;
    float inv = 1.f / fmaxf((float)deg[i], 1.f);
    float sx = Hf[(size_t)n * HID + cA], sy = Hf[(size_t)n * HID + cB];
    if (MODE) {
      sx = bnrelu(bnrelu(sx, a2A, c2A), a3A, c3A);
      sy = bnrelu(bnrelu(sy, a2B, c2B), a3B, c3B);
    }
    float zx = sx + acc[i * 128 + cA] * inv;
    float zy = sy + acc[i * 128 + cB] * inv;
    Z[(size_t)n * HID + cA] = (bf16)zx;
    Z[(size_t)n * HID + cB] = (bf16)zy;
  }
}

// ---------------- GEMM: C = A @ W^T, bf16 weights, fused column stats ----------------
// AMODE 0: A bf16 (Z). AMODE 1: A f32 + relu(a*x+c) transform, then bf16.
// Hout (optional): bf16 copy of C for next layer's gather.
template<int AMODE>
__global__ __launch_bounds__(256)
void gemm_k(const void* __restrict__ Asrc,
            const float* __restrict__ acIn, const float* __restrict__ g, const float* __restrict__ b,
            float invN,
            const bf16* __restrict__ Wb, float* __restrict__ C,
            float* __restrict__ accumOut, int Nrows, bf16* __restrict__ Hout) {
  __shared__ float sA[128], sC[128], sSum[128], sSq[128];
  int tid = threadIdx.x;
  if (tid < 128) {
    sSum[tid] = 0.f; sSq[tid] = 0.f;
    if (AMODE) {
      float mu = acIn[tid] * invN;
      float var = fmaxf(acIn[128 + tid] * invN - mu * mu, 0.f);
      float a = g[tid] * rsqrtf(var + BN_EPS);
      sA[tid] = a; sC[tid] = fmaf(-a, mu, b[tid]);
    }
  }
  __syncthreads();
  int wv = tid >> 6, lane = tid & 63;
  int lm = lane & 15, lg = lane >> 4;
  int rowbase = blockIdx.x * 128 + wv * 32;
  f32x4 acc[2][8] = {};
#pragma unroll
  for (int kk = 0; kk < 4; ++kk) {
    int kb = kk * 32 + lg * 8;
    bf16x8 af[2];
    if (AMODE == 0) {
      const bf16* Zp = (const bf16*)Asrc;
#pragma unroll
      for (int rt = 0; rt < 2; ++rt) {
        int row = rowbase + rt * 16 + lm; if (row > Nrows - 1) row = Nrows - 1;
        af[rt] = *(const bf16x8*)(Zp + (size_t)row * HID + kb);
      }
    } else {
      const float* Tp = (const float*)Asrc;
      float4 a0 = *(const float4*)(sA + kb), a1 = *(const float4*)(sA + kb + 4);
      float4 q0 = *(const float4*)(sC + kb), q1 = *(const float4*)(sC + kb + 4);
#pragma unroll
      for (int rt = 0; rt < 2; ++rt) {
        int row = rowbase + rt * 16 + lm; if (row > Nrows - 1) row = Nrows - 1;
        const float* p = Tp + (size_t)row * HID + kb;
        float4 x0 = *(const float4*)p, x1 = *(const float4*)(p + 4);
        bf16x8 f;
        f[0] = (bf16)bnrelu(x0.x, a0.x, q0.x); f[1] = (bf16)bnrelu(x0.y, a0.y, q0.y);
        f[2] = (bf16)bnrelu(x0.z, a0.z, q0.z); f[3] = (bf16)bnrelu(x0.w, a0.w, q0.w);
        f[4] = (bf16)bnrelu(x1.x, a1.x, q1.x); f[5] = (bf16)bnrelu(x1.y, a1.y, q1.y);
        f[6] = (bf16)bnrelu(x1.z, a1.z, q1.z); f[7] = (bf16)bnrelu(x1.w, a1.w, q1.w);
        af[rt] = f;
      }
    }
    bf16x8 bfr[8];
#pragma unroll
    for (int ct = 0; ct < 8; ++ct)
      bfr[ct] = *(const bf16x8*)(Wb + (size_t)(ct * 16 + lm) * HID + kb);
#pragma unroll
    for (int rt = 0; rt < 2; ++rt)
#pragma unroll
      for (int ct = 0; ct < 8; ++ct)
        acc[rt][ct] = __builtin_amdgcn_mfma_f32_16x16x32_bf16(af[rt], bfr[ct], acc[rt][ct], 0, 0, 0);
  }
#pragma unroll
  for (int ct = 0; ct < 8; ++ct) {
    int col = ct * 16 + lm;
    float ps = 0.f, pq = 0.f;
#pragma unroll
    for (int rt = 0; rt < 2; ++rt) {
#pragma unroll
      for (int i = 0; i < 4; ++i) {
        int row = rowbase + rt * 16 + lg * 4 + i;
        if (row < Nrows) {
          float v = acc[rt][ct][i];
          C[(size_t)row * HID + col] = v;
          if (Hout) Hout[(size_t)row * HID + col] = (bf16)v;
          ps += v; pq = fmaf(v, v, pq);
        }
      }
    }
    ps += __shfl_xor(ps, 16, 64); ps += __shfl_xor(ps, 32, 64);
    pq += __shfl_xor(pq, 16, 64); pq += __shfl_xor(pq, 32, 64);
    if (lane < 16) { atomicAdd(&sSum[col], ps); atomicAdd(&sSq[col], pq); }
  }
  __syncthreads();
  if (tid < 128) {
    atomicAdd(&accumOut[tid], sSum[tid]);
    atomicAdd(&accumOut[128 + tid], sSq[tid]);
  }
}

// ---------------- stats of relu(a*x+c) (outer BN input), coefs inline ----------------
__global__ __launch_bounds__(256)
void stats1_k(const float* __restrict__ T, const float* __restrict__ acIn,
              const float* __restrict__ g, const float* __restrict__ b, float invN,
              float* __restrict__ accumOut, int Nrows) {
  int col = threadIdx.x & 127, half = threadIdx.x >> 7;
  float mu = acIn[col] * invN;
  float var = fmaxf(acIn[128 + col] * invN - mu * mu, 0.f);
  float av = g[col] * rsqrtf(var + BN_EPS);
  float cv = fmaf(-av, mu, b[col]);
  float s = 0.f, sq = 0.f;
  for (int r = blockIdx.x * 2 + half; r < Nrows; r += gridDim.x * 2) {
    float x = T[(size_t)r * HID + col];
    x = fmaxf(fmaf(av, x, cv), 0.f);
    s += x; sq = fmaf(x, x, sq);
  }
  __shared__ float sb[256], qb[256];
  sb[threadIdx.x] = s; qb[threadIdx.x] = sq;
  __syncthreads();
  if (half == 0) {
    s += sb[threadIdx.x + 128]; sq += qb[threadIdx.x + 128];
    atomicAdd(&accumOut[col], s); atomicAdd(&accumOut[128 + col], sq);
  }
}

// ---------------- fused link predictor ----------------
__global__ __launch_bounds__(256)
void pred_k(const float* __restrict__ T, const float* __restrict__ acIn,
            const float* __restrict__ g, const float* __restrict__ b, float invN,
            const int* __restrict__ ps, const int* __restrict__ pd,
            const int* __restrict__ ns, const int* __restrict__ nd,
            const bf16* __restrict__ W1b, const float* __restrict__ b1p,
            const bf16* __restrict__ W2b, const float* __restrict__ b2p,
            const float* __restrict__ w3, const float* __restrict__ b3,
            float* __restrict__ out, int Pn) {
  __shared__ bf16 At[128 * 128];
  __shared__ float sAp[128], sCp[128];
  int tid = threadIdx.x;
  if (tid < 128) {
    float mu = acIn[tid] * invN;
    float var = fmaxf(acIn[128 + tid] * invN - mu * mu, 0.f);
    float a = g[tid] * rsqrtf(var + BN_EPS);
    sAp[tid] = a; sCp[tid] = fmaf(-a, mu, b[tid]);
  }
  __syncthreads();
  int q0 = blockIdx.x * 128;
  {
    int r = tid >> 1;
    int q = q0 + r;
    int cb = (tid & 1) * 64;
    if (q < 2 * Pn) {
      int s, d;
      if (q < Pn) { s = ps[q]; d = pd[q]; } else { s = ns[q - Pn]; d = nd[q - Pn]; }
      const float* rs_ = T + (size_t)s * HID;
      const float* rd_ = T + (size_t)d * HID;
      for (int c = cb; c < cb + 64; c += 4) {
        float4 xs = *(const float4*)(rs_ + c);
        float4 xd = *(const float4*)(rd_ + c);
        float4 av = *(const float4*)(sAp + c);
        float4 cv = *(const float4*)(sCp + c);
        float t0 = bnrelu(xs.x, av.x, cv.x) * bnrelu(xd.x, av.x, cv.x);
        float t1 = bnrelu(xs.y, av.y, cv.y) * bnrelu(xd.y, av.y, cv.y);
        float t2 = bnrelu(xs.z, av.z, cv.z) * bnrelu(xd.z, av.z, cv.z);
        float t3 = bnrelu(xs.w, av.w, cv.w) * bnrelu(xd.w, av.w, cv.w);
        union { bf16 h[4]; unsigned long long u; } pk;
        pk.h[0] = (bf16)t0; pk.h[1] = (bf16)t1; pk.h[2] = (bf16)t2; pk.h[3] = (bf16)t3;
        unsigned addr = (unsigned)(r * 256 + c * 2);
        addr ^= (unsigned)((r & 7) << 4);
        *(unsigned long long*)((char*)At + addr) = pk.u;
      }
    } else {
      for (int c = cb; c < cb + 64; c += 4) {
        unsigned addr = (unsigned)(r * 256 + c * 2);
        addr ^= (unsigned)((r & 7) << 4);
        *(unsigned long long*)((char*)At + addr) = 0ull;
      }
    }
  }
  __syncthreads();
  int wv = tid >> 6, lane = tid & 63;
  int lm = lane & 15, lg = lane >> 4;
  const f32x4 vzero = {0.f, 0.f, 0.f, 0.f};
  f32x4 acc[2][8];
#pragma unroll
  for (int r = 0; r < 2; ++r) for (int c = 0; c < 8; ++c) acc[r][c] = vzero;
#pragma unroll
  for (int kk = 0; kk < 4; ++kk) {
    bf16x8 af[2];
#pragma unroll
    for (int rt = 0; rt < 2; ++rt) {
      int row = wv * 32 + rt * 16 + lm;
      unsigned addr = (unsigned)(row * 256 + kk * 64 + lg * 16);
      addr ^= (unsigned)((row & 7) << 4);
      af[rt] = *(const bf16x8*)((char*)At + addr);
    }
    bf16x8 bfr[8];
#pragma unroll
    for (int ct = 0; ct < 8; ++ct)
      bfr[ct] = *(const bf16x8*)(W1b + (size_t)(ct * 16 + lm) * HID + kk * 32 + lg * 8);
#pragma unroll
    for (int rt = 0; rt < 2; ++rt)
#pragma unroll
      for (int ct = 0; ct < 8; ++ct)
        acc[rt][ct] = __builtin_amdgcn_mfma_f32_16x16x32_bf16(af[rt], bfr[ct], acc[rt][ct], 0, 0, 0);
  }
  __syncthreads();
#pragma unroll
  for (int rt = 0; rt < 2; ++rt)
#pragma unroll
    for (int ct = 0; ct < 8; ++ct) {
      int col = ct * 16 + lm;
      float bb = b1p[col];
#pragma unroll
      for (int i = 0; i < 4; ++i) {
        int row = wv * 32 + rt * 16 + lg * 4 + i;
        float v = fmaxf(acc[rt][ct][i] + bb, 0.f);
        unsigned addr = (unsigned)(row * 256 + col * 2);
        addr ^= (unsigned)((row & 7) << 4);
        *(bf16*)((char*)At + addr) = (bf16)v;
      }
    }
  __syncthreads();
#pragma unroll
  for (int r = 0; r < 2; ++r) for (int c = 0; c < 8; ++c) acc[r][c] = vzero;
#pragma unroll
  for (int kk = 0; kk < 4; ++kk) {
    bf16x8 af[2];
#pragma unroll
    for (int rt = 0; rt < 2; ++rt) {
      int row = wv * 32 + rt * 16 + lm;
      unsigned addr = (unsigned)(row * 256 + kk * 64 + lg * 16);
      addr ^= (unsigned)((row & 7) << 4);
      af[rt] = *(const bf16x8*)((char*)At + addr);
    }
    bf16x8 bfr[8];
#pragma unroll
    for (int ct = 0; ct < 8; ++ct)
      bfr[ct] = *(const bf16x8*)(W2b + (size_t)(ct * 16 + lm) * HID + kk * 32 + lg * 8);
#pragma unroll
    for (int rt = 0; rt < 2; ++rt)
#pragma unroll
      for (int ct = 0; ct < 8; ++ct)
        acc[rt][ct] = __builtin_amdgcn_mfma_f32_16x16x32_bf16(af[rt], bfr[ct], acc[rt][ct], 0, 0, 0);
  }
  float b2v[8], w3v[8];
#pragma unroll
  for (int ct = 0; ct < 8; ++ct) { b2v[ct] = b2p[ct * 16 + lm]; w3v[ct] = w3[ct * 16 + lm]; }
  float b3s = b3[0];
#pragma unroll
  for (int rt = 0; rt < 2; ++rt) {
#pragma unroll
    for (int i = 0; i < 4; ++i) {
      float p = 0.f;
#pragma unroll
      for (int ct = 0; ct < 8; ++ct)
        p += fmaxf(acc[rt][ct][i] + b2v[ct], 0.f) * w3v[ct];
      p += __shfl_xor(p, 1); p += __shfl_xor(p, 2);
      p += __shfl_xor(p, 4); p += __shfl_xor(p, 8);
      int row = wv * 32 + rt * 16 + lg * 4 + i;
      int q = q0 + row;
      if (lm == 0 && q < 2 * Pn) out[q] = p + b3s;
    }
  }
}

// ---------------- launcher ----------------
extern "C" void kernel_launch(void* const* d_in, const int* in_sizes, int n_in,
                              void* d_out, int out_size, void* d_ws, size_t ws_size,
                              hipStream_t stream) {
  const float* x  = (const float*)d_in[0];
  const int* src  = (const int*)d_in[1];
  const int* dst  = (const int*)d_in[2];
  const int* ps   = (const int*)d_in[3];
  const int* pd   = (const int*)d_in[4];
  const int* ns   = (const int*)d_in[5];
  const int* nd   = (const int*)d_in[6];
  const float* W0 = (const float*)d_in[7];
  const float* W1 = (const float*)d_in[8];
  const float* g_mlp   = (const float*)d_in[9];
  const float* b_mlp   = (const float*)d_in[10];
  const float* g_apply = (const float*)d_in[11];
  const float* b_apply = (const float*)d_in[12];
  const float* g_out   = (const float*)d_in[13];
  const float* b_out   = (const float*)d_in[14];
  const float* pW1 = (const float*)d_in[15];
  const float* pb1 = (const float*)d_in[16];
  const float* pW2 = (const float*)d_in[17];
  const float* pb2 = (const float*)d_in[18];
  const float* pW3 = (const float*)d_in[19];
  const float* pb3 = (const float*)d_in[20];
  float* out = (float*)d_out;

  const int N = in_sizes[0] / HID;
  const int E = in_sizes[1];
  const int P = in_sizes[3];
  const int NB = (N + BWIDTH - 1) >> NBSHIFT;

  char* w = (char*)d_ws;
  size_t off = 0;
  auto alloc = [&](size_t bytes) -> void* {
    void* p = w + off;
    off = (off + bytes + 255) & ~(size_t)255;
    return p;
  };
  bf16*  Z   = (bf16*)alloc((size_t)N * HID * 2);
  float* TA  = (float*)alloc((size_t)N * HID * 4);
  float* TB  = (float*)alloc((size_t)N * HID * 4);
  bf16*  TBh = (bf16*)alloc((size_t)N * HID * 2);
  unsigned* ebuf = (unsigned*)alloc((size_t)E * 4);
  int*   boff = (int*)alloc((size_t)(NB + 1) * 4);
  int*   bcur = (int*)alloc((size_t)NB * 4);
  size_t zoff = off;
  int*   bcnt = (int*)alloc((size_t)NB * 4);
  float* accum = (float*)alloc(9 * 256 * 4);
  size_t zbytes = off - zoff;
  bf16*  Wb = (bf16*)alloc(8 * 16384 * 2);
  (void)ws_size; (void)n_in; (void)out_size;

  const float invN = 1.f / (float)N;

  hipMemsetAsync(w + zoff, 0, zbytes, stream);
  histB_k<<<256, 256, 0, stream>>>(dst, bcnt, E, NB);
  scanB_k<<<1, 1024, 0, stream>>>(bcnt, boff, bcur, NB);
  part_k<<<(E + 2047) / 2048, 256, 0, stream>>>(src, dst, bcur, ebuf, E, NB);
  wconv_k<<<128, 256, 0, stream>>>(W0, W1, pW1, pW2, Wb);

  int gridG = (N + 127) / 128;

  for (int l = 0; l < 3; ++l) {
    int s0 = l * 3 + 0, s1 = l * 3 + 1, s2 = l * 3 + 2;
    if (l == 0)
      aggb_k<0><<<NB, 256, 0, stream>>>(x, nullptr,
                                        nullptr, nullptr, nullptr,
                                        nullptr, nullptr, nullptr, invN,
                                        boff, ebuf, Z, N);
    else {
      int p1 = (l - 1) * 3 + 1, p2 = (l - 1) * 3 + 2;
      aggb_k<1><<<NB, 256, 0, stream>>>(TB, TBh,
                                        accum + p1 * 256, g_apply + (l - 1) * HID, b_apply + (l - 1) * HID,
                                        accum + p2 * 256, g_out + (l - 1) * HID, b_out + (l - 1) * HID,
                                        invN, boff, ebuf, Z, N);
    }
    gemm_k<0><<<gridG, 256, 0, stream>>>(Z, nullptr, nullptr, nullptr, invN,
                                         Wb + (size_t)l * 16384, TA, accum + s0 * 256, N, nullptr);
    gemm_k<1><<<gridG, 256, 0, stream>>>(TA, accum + s0 * 256, g_mlp + l * HID, b_mlp + l * HID, invN,
                                         Wb + (size_t)(3 + l) * 16384, TB, accum + s1 * 256, N,
                                         (l < 2) ? TBh : nullptr);
    if (l < 2)
      stats1_k<<<512, 256, 0, stream>>>(TB, accum + s1 * 256, g_apply + l * HID, b_apply + l * HID,
                                        invN, accum + s2 * 256, N);
  }
  int gridP = (2 * P + 127) / 128;
  pred_k<<<gridP, 256, 0, stream>>>(TB, accum + 7 * 256, g_apply + 2 * HID, b_apply + 2 * HID, invN,
                                    ps, pd, ns, nd,
                                    Wb + (size_t)6 * 16384, pb1,
                                    Wb + (size_t)7 * 16384, pb2,
                                    pW3, pb3, out, P);
}

// Round 6
// 1048.357 us; speedup vs baseline: 4.4525x; 4.4525x over previous
//
#include <hip/hip_runtime.h>

#define HID 128
#define BN_EPS 1e-5f

typedef __bf16 bf16;
typedef __attribute__((ext_vector_type(8))) __bf16 bf16x8;
typedef __attribute__((ext_vector_type(4))) float f32x4;

__device__ __forceinline__ float bnrelu(float x, float a, float c) {
  return fmaxf(fmaf(a, x, c), 0.f);
}

// ---------------- per-node histogram ----------------
__global__ void hist_k(const int* __restrict__ dst, int* __restrict__ cnt, int E) {
  int i = blockIdx.x * blockDim.x + threadIdx.x;
  if (i < E) atomicAdd(&cnt[dst[i]], 1);
}

// block partial sums (1024 elems / block)
__global__ __launch_bounds__(256)
void scan1_k(const int* __restrict__ cnt, int* __restrict__ bsum, int Nn) {
  __shared__ int red[4];
  int tid = threadIdx.x;
  int base = blockIdx.x * 1024;
  int s = 0;
#pragma unroll
  for (int u = 0; u < 4; ++u) {
    int i = base + u * 256 + tid;
    if (i < Nn) s += cnt[i];
  }
#pragma unroll
  for (int d = 1; d < 64; d <<= 1) s += __shfl_xor(s, d, 64);
  int lane = tid & 63, wv = tid >> 6;
  if (lane == 0) red[wv] = s;
  __syncthreads();
  if (tid == 0) bsum[blockIdx.x] = red[0] + red[1] + red[2] + red[3];
}

// exclusive scan of block sums, in place (single wave)
__global__ void scan2_k(int* __restrict__ bsum, int G) {
  int lane = threadIdx.x;
  int carry = 0;
  for (int base = 0; base < G; base += 64) {
    int i = base + lane;
    int v = (i < G) ? bsum[i] : 0;
    int x = v;
#pragma unroll
    for (int d = 1; d < 64; d <<= 1) { int t = __shfl_up(x, d, 64); if (lane >= d) x += t; }
    if (i < G) bsum[i] = carry + x - v;
    carry += __shfl(x, 63, 64);
  }
}

// final scan: row_start
__global__ __launch_bounds__(256)
void scan3_k(const int* __restrict__ cnt, const int* __restrict__ boff,
             int* __restrict__ row_start, int Nn, int E) {
  __shared__ int wtot[4];
  int tid = threadIdx.x, lane = tid & 63, wv = tid >> 6;
  int i0 = blockIdx.x * 1024 + tid * 4;
  int t0 = 0, t1 = 0, t2 = 0, t3 = 0;
  if (i0 + 3 < Nn) {
    int4 v = *(const int4*)(cnt + i0);
    t0 = v.x; t1 = v.y; t2 = v.z; t3 = v.w;
  } else {
    if (i0     < Nn) t0 = cnt[i0];
    if (i0 + 1 < Nn) t1 = cnt[i0 + 1];
    if (i0 + 2 < Nn) t2 = cnt[i0 + 2];
    if (i0 + 3 < Nn) t3 = cnt[i0 + 3];
  }
  int tsum = t0 + t1 + t2 + t3;
  int x = tsum;
#pragma unroll
  for (int d = 1; d < 64; d <<= 1) { int t = __shfl_up(x, d, 64); if (lane >= d) x += t; }
  if (lane == 63) wtot[wv] = x;
  __syncthreads();
  int wo = 0;
  for (int k = 0; k < wv; ++k) wo += wtot[k];
  int base = boff[blockIdx.x] + wo + x - tsum;
  if (i0     < Nn) row_start[i0] = base;
  if (i0 + 1 < Nn) row_start[i0 + 1] = base + t0;
  if (i0 + 2 < Nn) row_start[i0 + 2] = base + t0 + t1;
  if (i0 + 3 < Nn) row_start[i0 + 3] = base + t0 + t1 + t2;
  if (blockIdx.x == 0 && tid == 0) row_start[Nn] = E;
}

// ---------------- coarse-bucket cursor init (bucket = 2048 nodes) ----------------
__global__ void init64_k(const int* __restrict__ row_start, int* __restrict__ bcur64,
                         int Nn, int NB2) {
  int i = threadIdx.x;
  if (i < NB2) {
    int n = i << 11; if (n > Nn) n = Nn;
    bcur64[i] = row_start[n];
  }
}

// ---------------- partition edges into 2048-node buckets, packed (dl<<17)|src ----------------
__global__ __launch_bounds__(256)
void part64_k(const int* __restrict__ src, const int* __restrict__ dst,
              int* __restrict__ bcur64, unsigned* __restrict__ ebuf2, int E) {
  __shared__ int lcnt[64], gbase[64], lcur[64];
  int tid = threadIdx.x;
  if (tid < 64) { lcnt[tid] = 0; lcur[tid] = 0; }
  __syncthreads();
  int base = blockIdx.x * 2048;
  int ok[8]; unsigned pk[8]; int bk[8];
#pragma unroll
  for (int u = 0; u < 8; ++u) {
    int e = base + u * 256 + tid;
    if (e < E) {
      int s = src[e], d = dst[e];
      ok[u] = 1; bk[u] = d >> 11;
      pk[u] = ((unsigned)(d & 2047) << 17) | (unsigned)s;
      atomicAdd(&lcnt[bk[u]], 1);
    } else ok[u] = 0;
  }
  __syncthreads();
  if (tid < 64 && lcnt[tid]) gbase[tid] = atomicAdd(&bcur64[tid], lcnt[tid]);
  __syncthreads();
#pragma unroll
  for (int u = 0; u < 8; ++u) if (ok[u]) {
    int sl = atomicAdd(&lcur[bk[u]], 1);
    ebuf2[gbase[bk[u]] + sl] = pk[u];
  }
}

// ---------------- bucket -> CSR (one block owns one 2048-node bucket) ----------------
__global__ __launch_bounds__(1024)
void fill2_k(const unsigned* __restrict__ ebuf2, const int* __restrict__ row_start,
             int* __restrict__ csr, int Nn) {
  __shared__ int ncur[2048];
  int tid = threadIdx.x;
  ncur[tid] = 0; ncur[tid + 1024] = 0;
  __syncthreads();
  int nb0 = blockIdx.x << 11;
  int hi = nb0 + 2048; if (hi > Nn) hi = Nn;
  int beg = row_start[nb0], end = row_start[hi];
  for (int e = beg + tid; e < end; e += 1024) {
    unsigned v = ebuf2[e];
    int dl = v >> 17, s = (int)(v & 0x1FFFF);
    int p = atomicAdd(&ncur[dl], 1);
    csr[row_start[nb0 + dl] + p] = s;
  }
}

// ---------------- weight convert to bf16 ----------------
__global__ __launch_bounds__(256)
void wconv_k(const float* __restrict__ W0, const float* __restrict__ W1,
             const float* __restrict__ pW1, const float* __restrict__ pW2,
             bf16* __restrict__ Wb) {
  int idx = (blockIdx.x * 256 + threadIdx.x) * 4;
  int seg = idx >> 14, loc = idx & 16383;
  const float* srcp = seg < 3 ? W0 + (size_t)seg * 16384
                    : seg < 6 ? W1 + (size_t)(seg - 3) * 16384
                    : seg == 6 ? pW1 : pW2;
  float4 v = *(const float4*)(srcp + loc);
  union { bf16 h[4]; unsigned long long u; } pk;
  pk.h[0] = (bf16)v.x; pk.h[1] = (bf16)v.y; pk.h[2] = (bf16)v.z; pk.h[3] = (bf16)v.w;
  *(unsigned long long*)(Wb + idx) = pk.u;
}

// ---------------- aggregation (+z, bf16 output), unroll-8 ----------------
// MODE 0: h = H raw.  MODE 1: h = relu(a3*relu(a2*x+c2)+c3), coefs from accum slots
template<int MODE>
__global__ __launch_bounds__(256)
void agg_k(const float* __restrict__ H,
           const float* __restrict__ ac1, const float* __restrict__ g1, const float* __restrict__ b1,
           const float* __restrict__ ac2, const float* __restrict__ g2, const float* __restrict__ b2,
           float invN,
           const int* __restrict__ row_start, const int* __restrict__ csr,
           bf16* __restrict__ Z, int Nn) {
  __shared__ float sA2[128], sC2[128], sA3[128], sC3[128];
  int tid = threadIdx.x;
  if (MODE) {
    if (tid < 128) {
      float mu = ac1[tid] * invN;
      float var = fmaxf(ac1[128 + tid] * invN - mu * mu, 0.f);
      float a = g1[tid] * rsqrtf(var + BN_EPS);
      sA2[tid] = a; sC2[tid] = fmaf(-a, mu, b1[tid]);
      mu = ac2[tid] * invN;
      var = fmaxf(ac2[128 + tid] * invN - mu * mu, 0.f);
      a = g2[tid] * rsqrtf(var + BN_EPS);
      sA3[tid] = a; sC3[tid] = fmaf(-a, mu, b2[tid]);
    }
    __syncthreads();
  }
  int wv = tid >> 6, lane = tid & 63;
  int n = blockIdx.x * 4 + wv;
  if (n >= Nn) return;
  int c0 = lane * 2;
  float A2x = 0, A2y = 0, C2x = 0, C2y = 0, A3x = 0, A3y = 0, C3x = 0, C3y = 0;
  if (MODE) {
    A2x = sA2[c0]; A2y = sA2[c0 + 1]; C2x = sC2[c0]; C2y = sC2[c0 + 1];
    A3x = sA3[c0]; A3y = sA3[c0 + 1]; C3x = sC3[c0]; C3y = sC3[c0 + 1];
  }
  int beg = row_start[n], end = row_start[n + 1];
  float2 hn = *(const float2*)(H + (size_t)n * HID + c0);
  float inv = 1.f / fmaxf((float)(end - beg), 1.f);
  float ax0 = 0, ay0 = 0, ax1 = 0, ay1 = 0, ax2 = 0, ay2 = 0, ax3 = 0, ay3 = 0;
  int j = beg;
  for (; j + 8 <= end; j += 8) {
    int s0 = csr[j], s1 = csr[j + 1], s2 = csr[j + 2], s3 = csr[j + 3];
    int s4 = csr[j + 4], s5 = csr[j + 5], s6 = csr[j + 6], s7 = csr[j + 7];
    float2 v0 = *(const float2*)(H + (size_t)s0 * HID + c0);
    float2 v1 = *(const float2*)(H + (size_t)s1 * HID + c0);
    float2 v2 = *(const float2*)(H + (size_t)s2 * HID + c0);
    float2 v3 = *(const float2*)(H + (size_t)s3 * HID + c0);
    float2 v4 = *(const float2*)(H + (size_t)s4 * HID + c0);
    float2 v5 = *(const float2*)(H + (size_t)s5 * HID + c0);
    float2 v6 = *(const float2*)(H + (size_t)s6 * HID + c0);
    float2 v7 = *(const float2*)(H + (size_t)s7 * HID + c0);
    if (MODE) {
      v0.x = bnrelu(bnrelu(v0.x, A2x, C2x), A3x, C3x); v0.y = bnrelu(bnrelu(v0.y, A2y, C2y), A3y, C3y);
      v1.x = bnrelu(bnrelu(v1.x, A2x, C2x), A3x, C3x); v1.y = bnrelu(bnrelu(v1.y, A2y, C2y), A3y, C3y);
      v2.x = bnrelu(bnrelu(v2.x, A2x, C2x), A3x, C3x); v2.y = bnrelu(bnrelu(v2.y, A2y, C2y), A3y, C3y);
      v3.x = bnrelu(bnrelu(v3.x, A2x, C2x), A3x, C3x); v3.y = bnrelu(bnrelu(v3.y, A2y, C2y), A3y, C3y);
      v4.x = bnrelu(bnrelu(v4.x, A2x, C2x), A3x, C3x); v4.y = bnrelu(bnrelu(v4.y, A2y, C2y), A3y, C3y);
      v5.x = bnrelu(bnrelu(v5.x, A2x, C2x), A3x, C3x); v5.y = bnrelu(bnrelu(v5.y, A2y, C2y), A3y, C3y);
      v6.x = bnrelu(bnrelu(v6.x, A2x, C2x), A3x, C3x); v6.y = bnrelu(bnrelu(v6.y, A2y, C2y), A3y, C3y);
      v7.x = bnrelu(bnrelu(v7.x, A2x, C2x), A3x, C3x); v7.y = bnrelu(bnrelu(v7.y, A2y, C2y), A3y, C3y);
    }
    ax0 += v0.x; ay0 += v0.y; ax1 += v1.x; ay1 += v1.y;
    ax2 += v2.x; ay2 += v2.y; ax3 += v3.x; ay3 += v3.y;
    ax0 += v4.x; ay0 += v4.y; ax1 += v5.x; ay1 += v5.y;
    ax2 += v6.x; ay2 += v6.y; ax3 += v7.x; ay3 += v7.y;
  }
  for (; j < end; ++j) {
    int s = csr[j];
    float2 v = *(const float2*)(H + (size_t)s * HID + c0);
    if (MODE) {
      v.x = bnrelu(bnrelu(v.x, A2x, C2x), A3x, C3x);
      v.y = bnrelu(bnrelu(v.y, A2y, C2y), A3y, C3y);
    }
    ax0 += v.x; ay0 += v.y;
  }
  float ax = (ax0 + ax1) + (ax2 + ax3);
  float ay = (ay0 + ay1) + (ay2 + ay3);
  float hx = hn.x, hy = hn.y;
  if (MODE) {
    hx = bnrelu(bnrelu(hx, A2x, C2x), A3x, C3x);
    hy = bnrelu(bnrelu(hy, A2y, C2y), A3y, C3y);
  }
  float zx = hx + ax * inv, zy = hy + ay * inv;
  union { bf16 h[2]; unsigned u; } pk;
  pk.h[0] = (bf16)zx; pk.h[1] = (bf16)zy;
  *(unsigned*)((char*)Z + ((size_t)n * HID + c0) * 2) = pk.u;
}

// ---------------- GEMM: C = A @ W^T, bf16 weights, fused column stats ----------------
// AMODE 0: A bf16 (Z). AMODE 1: A f32 + relu(a*x+c) transform, then bf16.
template<int AMODE>
__global__ __launch_bounds__(256)
void gemm_k(const void* __restrict__ Asrc,
            const float* __restrict__ acIn, const float* __restrict__ g, const float* __restrict__ b,
            float invN,
            const bf16* __restrict__ Wb, float* __restrict__ C,
            float* __restrict__ accumOut, int Nrows) {
  __shared__ float sA[128], sC[128], sSum[128], sSq[128];
  int tid = threadIdx.x;
  if (tid < 128) {
    sSum[tid] = 0.f; sSq[tid] = 0.f;
    if (AMODE) {
      float mu = acIn[tid] * invN;
      float var = fmaxf(acIn[128 + tid] * invN - mu * mu, 0.f);
      float a = g[tid] * rsqrtf(var + BN_EPS);
      sA[tid] = a; sC[tid] = fmaf(-a, mu, b[tid]);
    }
  }
  __syncthreads();
  int wv = tid >> 6, lane = tid & 63;
  int lm = lane & 15, lg = lane >> 4;
  int rowbase = blockIdx.x * 128 + wv * 32;
  f32x4 acc[2][8] = {};
#pragma unroll
  for (int kk = 0; kk < 4; ++kk) {
    int kb = kk * 32 + lg * 8;
    bf16x8 af[2];
    if (AMODE == 0) {
      const bf16* Zp = (const bf16*)Asrc;
#pragma unroll
      for (int rt = 0; rt < 2; ++rt) {
        int row = rowbase + rt * 16 + lm; if (row > Nrows - 1) row = Nrows - 1;
        af[rt] = *(const bf16x8*)(Zp + (size_t)row * HID + kb);
      }
    } else {
      const float* Tp = (const float*)Asrc;
      float4 a0 = *(const float4*)(sA + kb), a1 = *(const float4*)(sA + kb + 4);
      float4 q0 = *(const float4*)(sC + kb), q1 = *(const float4*)(sC + kb + 4);
#pragma unroll
      for (int rt = 0; rt < 2; ++rt) {
        int row = rowbase + rt * 16 + lm; if (row > Nrows - 1) row = Nrows - 1;
        const float* p = Tp + (size_t)row * HID + kb;
        float4 x0 = *(const float4*)p, x1 = *(const float4*)(p + 4);
        bf16x8 f;
        f[0] = (bf16)bnrelu(x0.x, a0.x, q0.x); f[1] = (bf16)bnrelu(x0.y, a0.y, q0.y);
        f[2] = (bf16)bnrelu(x0.z, a0.z, q0.z); f[3] = (bf16)bnrelu(x0.w, a0.w, q0.w);
        f[4] = (bf16)bnrelu(x1.x, a1.x, q1.x); f[5] = (bf16)bnrelu(x1.y, a1.y, q1.y);
        f[6] = (bf16)bnrelu(x1.z, a1.z, q1.z); f[7] = (bf16)bnrelu(x1.w, a1.w, q1.w);
        af[rt] = f;
      }
    }
    bf16x8 bfr[8];
#pragma unroll
    for (int ct = 0; ct < 8; ++ct)
      bfr[ct] = *(const bf16x8*)(Wb + (size_t)(ct * 16 + lm) * HID + kb);
#pragma unroll
    for (int rt = 0; rt < 2; ++rt)
#pragma unroll
      for (int ct = 0; ct < 8; ++ct)
        acc[rt][ct] = __builtin_amdgcn_mfma_f32_16x16x32_bf16(af[rt], bfr[ct], acc[rt][ct], 0, 0, 0);
  }
#pragma unroll
  for (int ct = 0; ct < 8; ++ct) {
    int col = ct * 16 + lm;
    float ps = 0.f, pq = 0.f;
#pragma unroll
    for (int rt = 0; rt < 2; ++rt) {
#pragma unroll
      for (int i = 0; i < 4; ++i) {
        int row = rowbase + rt * 16 + lg * 4 + i;
        if (row < Nrows) {
          float v = acc[rt][ct][i];
          C[(size_t)row * HID + col] = v;
          ps += v; pq = fmaf(v, v, pq);
        }
      }
    }
    ps += __shfl_xor(ps, 16, 64); ps += __shfl_xor(ps, 32, 64);
    pq += __shfl_xor(pq, 16, 64); pq += __shfl_xor(pq, 32, 64);
    if (lane < 16) { atomicAdd(&sSum[col], ps); atomicAdd(&sSq[col], pq); }
  }
  __syncthreads();
  if (tid < 128) {
    atomicAdd(&accumOut[tid], sSum[tid]);
    atomicAdd(&accumOut[128 + tid], sSq[tid]);
  }
}

// ---------------- stats of relu(a*x+c) (outer BN input), coefs inline ----------------
__global__ __launch_bounds__(256)
void stats1_k(const float* __restrict__ T, const float* __restrict__ acIn,
              const float* __restrict__ g, const float* __restrict__ b, float invN,
              float* __restrict__ accumOut, int Nrows) {
  int col = threadIdx.x & 127, half = threadIdx.x >> 7;
  float mu = acIn[col] * invN;
  float var = fmaxf(acIn[128 + col] * invN - mu * mu, 0.f);
  float av = g[col] * rsqrtf(var + BN_EPS);
  float cv = fmaf(-av, mu, b[col]);
  float s = 0.f, sq = 0.f;
  for (int r = blockIdx.x * 2 + half; r < Nrows; r += gridDim.x * 2) {
    float x = T[(size_t)r * HID + col];
    x = fmaxf(fmaf(av, x, cv), 0.f);
    s += x; sq = fmaf(x, x, sq);
  }
  __shared__ float sb[256], qb[256];
  sb[threadIdx.x] = s; qb[threadIdx.x] = sq;
  __syncthreads();
  if (half == 0) {
    s += sb[threadIdx.x + 128]; sq += qb[threadIdx.x + 128];
    atomicAdd(&accumOut[col], s); atomicAdd(&accumOut[128 + col], sq);
  }
}

// ---------------- fused link predictor ----------------
__global__ __launch_bounds__(256)
void pred_k(const float* __restrict__ T, const float* __restrict__ acIn,
            const float* __restrict__ g, const float* __restrict__ b, float invN,
            const int* __restrict__ ps, const int* __restrict__ pd,
            const int* __restrict__ ns, const int* __restrict__ nd,
            const bf16* __restrict__ W1b, const float* __restrict__ b1p,
            const bf16* __restrict__ W2b, const float* __restrict__ b2p,
            const float* __restrict__ w3, const float* __restrict__ b3,
            float* __restrict__ out, int Pn) {
  __shared__ bf16 At[128 * 128];
  __shared__ float sAp[128], sCp[128];
  int tid = threadIdx.x;
  if (tid < 128) {
    float mu = acIn[tid] * invN;
    float var = fmaxf(acIn[128 + tid] * invN - mu * mu, 0.f);
    float a = g[tid] * rsqrtf(var + BN_EPS);
    sAp[tid] = a; sCp[tid] = fmaf(-a, mu, b[tid]);
  }
  __syncthreads();
  int q0 = blockIdx.x * 128;
  {
    int r = tid >> 1;
    int q = q0 + r;
    int cb = (tid & 1) * 64;
    if (q < 2 * Pn) {
      int s, d;
      if (q < Pn) { s = ps[q]; d = pd[q]; } else { s = ns[q - Pn]; d = nd[q - Pn]; }
      const float* rs_ = T + (size_t)s * HID;
      const float* rd_ = T + (size_t)d * HID;
      for (int c = cb; c < cb + 64; c += 4) {
        float4 xs = *(const float4*)(rs_ + c);
        float4 xd = *(const float4*)(rd_ + c);
        float4 av = *(const float4*)(sAp + c);
        float4 cv = *(const float4*)(sCp + c);
        float t0 = bnrelu(xs.x, av.x, cv.x) * bnrelu(xd.x, av.x, cv.x);
        float t1 = bnrelu(xs.y, av.y, cv.y) * bnrelu(xd.y, av.y, cv.y);
        float t2 = bnrelu(xs.z, av.z, cv.z) * bnrelu(xd.z, av.z, cv.z);
        float t3 = bnrelu(xs.w, av.w, cv.w) * bnrelu(xd.w, av.w, cv.w);
        union { bf16 h[4]; unsigned long long u; } pk;
        pk.h[0] = (bf16)t0; pk.h[1] = (bf16)t1; pk.h[2] = (bf16)t2; pk.h[3] = (bf16)t3;
        unsigned addr = (unsigned)(r * 256 + c * 2);
        addr ^= (unsigned)((r & 7) << 4);
        *(unsigned long long*)((char*)At + addr) = pk.u;
      }
    } else {
      for (int c = cb; c < cb + 64; c += 4) {
        unsigned addr = (unsigned)(r * 256 + c * 2);
        addr ^= (unsigned)((r & 7) << 4);
        *(unsigned long long*)((char*)At + addr) = 0ull;
      }
    }
  }
  __syncthreads();
  int wv = tid >> 6, lane = tid & 63;
  int lm = lane & 15, lg = lane >> 4;
  const f32x4 vzero = {0.f, 0.f, 0.f, 0.f};
  f32x4 acc[2][8];
#pragma unroll
  for (int r = 0; r < 2; ++r) for (int c = 0; c < 8; ++c) acc[r][c] = vzero;
#pragma unroll
  for (int kk = 0; kk < 4; ++kk) {
    bf16x8 af[2];
#pragma unroll
    for (int rt = 0; rt < 2; ++rt) {
      int row = wv * 32 + rt * 16 + lm;
      unsigned addr = (unsigned)(row * 256 + kk * 64 + lg * 16);
      addr ^= (unsigned)((row & 7) << 4);
      af[rt] = *(const bf16x8*)((char*)At + addr);
    }
    bf16x8 bfr[8];
#pragma unroll
    for (int ct = 0; ct < 8; ++ct)
      bfr[ct] = *(const bf16x8*)(W1b + (size_t)(ct * 16 + lm) * HID + kk * 32 + lg * 8);
#pragma unroll
    for (int rt = 0; rt < 2; ++rt)
#pragma unroll
      for (int ct = 0; ct < 8; ++ct)
        acc[rt][ct] = __builtin_amdgcn_mfma_f32_16x16x32_bf16(af[rt], bfr[ct], acc[rt][ct], 0, 0, 0);
  }
  __syncthreads();
#pragma unroll
  for (int rt = 0; rt < 2; ++rt)
#pragma unroll
    for (int ct = 0; ct < 8; ++ct) {
      int col = ct * 16 + lm;
      float bb = b1p[col];
#pragma unroll
      for (int i = 0; i < 4; ++i) {
        int row = wv * 32 + rt * 16 + lg * 4 + i;
        float v = fmaxf(acc[rt][ct][i] + bb, 0.f);
        unsigned addr = (unsigned)(row * 256 + col * 2);
        addr ^= (unsigned)((row & 7) << 4);
        *(bf16*)((char*)At + addr) = (bf16)v;
      }
    }
  __syncthreads();
#pragma unroll
  for (int r = 0; r < 2; ++r) for (int c = 0; c < 8; ++c) acc[r][c] = vzero;
#pragma unroll
  for (int kk = 0; kk < 4; ++kk) {
    bf16x8 af[2];
#pragma unroll
    for (int rt = 0; rt < 2; ++rt) {
      int row = wv * 32 + rt * 16 + lm;
      unsigned addr = (unsigned)(row * 256 + kk * 64 + lg * 16);
      addr ^= (unsigned)((row & 7) << 4);
      af[rt] = *(const bf16x8*)((char*)At + addr);
    }
    bf16x8 bfr[8];
#pragma unroll
    for (int ct = 0; ct < 8; ++ct)
      bfr[ct] = *(const bf16x8*)(W2b + (size_t)(ct * 16 + lm) * HID + kk * 32 + lg * 8);
#pragma unroll
    for (int rt = 0; rt < 2; ++rt)
#pragma unroll
      for (int ct = 0; ct < 8; ++ct)
        acc[rt][ct] = __builtin_amdgcn_mfma_f32_16x16x32_bf16(af[rt], bfr[ct], acc[rt][ct], 0, 0, 0);
  }
  float b2v[8], w3v[8];
#pragma unroll
  for (int ct = 0; ct < 8; ++ct) { b2v[ct] = b2p[ct * 16 + lm]; w3v[ct] = w3[ct * 16 + lm]; }
  float b3s = b3[0];
#pragma unroll
  for (int rt = 0; rt < 2; ++rt) {
#pragma unroll
    for (int i = 0; i < 4; ++i) {
      float p = 0.f;
#pragma unroll
      for (int ct = 0; ct < 8; ++ct)
        p += fmaxf(acc[rt][ct][i] + b2v[ct], 0.f) * w3v[ct];
      p += __shfl_xor(p, 1); p += __shfl_xor(p, 2);
      p += __shfl_xor(p, 4); p += __shfl_xor(p, 8);
      int row = wv * 32 + rt * 16 + lg * 4 + i;
      int q = q0 + row;
      if (lm == 0 && q < 2 * Pn) out[q] = p + b3s;
    }
  }
}

// ---------------- launcher ----------------
extern "C" void kernel_launch(void* const* d_in, const int* in_sizes, int n_in,
                              void* d_out, int out_size, void* d_ws, size_t ws_size,
                              hipStream_t stream) {
  const float* x  = (const float*)d_in[0];
  const int* src  = (const int*)d_in[1];
  const int* dst  = (const int*)d_in[2];
  const int* ps   = (const int*)d_in[3];
  const int* pd   = (const int*)d_in[4];
  const int* ns   = (const int*)d_in[5];
  const int* nd   = (const int*)d_in[6];
  const float* W0 = (const float*)d_in[7];
  const float* W1 = (const float*)d_in[8];
  const float* g_mlp   = (const float*)d_in[9];
  const float* b_mlp   = (const float*)d_in[10];
  const float* g_apply = (const float*)d_in[11];
  const float* b_apply = (const float*)d_in[12];
  const float* g_out   = (const float*)d_in[13];
  const float* b_out   = (const float*)d_in[14];
  const float* pW1 = (const float*)d_in[15];
  const float* pb1 = (const float*)d_in[16];
  const float* pW2 = (const float*)d_in[17];
  const float* pb2 = (const float*)d_in[18];
  const float* pW3 = (const float*)d_in[19];
  const float* pb3 = (const float*)d_in[20];
  float* out = (float*)d_out;

  const int N = in_sizes[0] / HID;
  const int E = in_sizes[1];
  const int P = in_sizes[3];
  const int NB2 = (N + 2047) >> 11;

  char* w = (char*)d_ws;
  size_t off = 0;
  auto alloc = [&](size_t bytes) -> void* {
    void* p = w + off;
    off = (off + bytes + 255) & ~(size_t)255;
    return p;
  };
  bf16*  Z   = (bf16*)alloc((size_t)N * HID * 2);
  float* TA  = (float*)alloc((size_t)N * HID * 4);
  float* TB  = (float*)alloc((size_t)N * HID * 4);
  int*   csr = (int*)alloc((size_t)E * 4);
  unsigned* ebuf2 = (unsigned*)alloc((size_t)E * 4);
  int*   row_start = (int*)alloc((size_t)(N + 1) * 4);
  size_t zoff = off;
  int*   cnt   = (int*)alloc((size_t)N * 4);
  float* accum = (float*)alloc(9 * 256 * 4);
  size_t zbytes = off - zoff;
  int*   bsum   = (int*)alloc(256 * 4);
  int*   bcur64 = (int*)alloc(64 * 4);
  bf16*  Wb = (bf16*)alloc(8 * 16384 * 2);
  (void)ws_size; (void)n_in; (void)out_size;

  const int G = (N + 1023) / 1024;
  const float invN = 1.f / (float)N;

  hipMemsetAsync(w + zoff, 0, zbytes, stream);
  int gridE = (E + 255) / 256;
  hist_k<<<gridE, 256, 0, stream>>>(dst, cnt, E);
  scan1_k<<<G, 256, 0, stream>>>(cnt, bsum, N);
  scan2_k<<<1, 64, 0, stream>>>(bsum, G);
  scan3_k<<<G, 256, 0, stream>>>(cnt, bsum, row_start, N, E);
  init64_k<<<1, 64, 0, stream>>>(row_start, bcur64, N, NB2);
  part64_k<<<(E + 2047) / 2048, 256, 0, stream>>>(src, dst, bcur64, ebuf2, E);
  fill2_k<<<NB2, 1024, 0, stream>>>(ebuf2, row_start, csr, N);
  wconv_k<<<128, 256, 0, stream>>>(W0, W1, pW1, pW2, Wb);

  int gridN4 = (N + 3) / 4;
  int gridG  = (N + 127) / 128;

  for (int l = 0; l < 3; ++l) {
    int s0 = l * 3 + 0, s1 = l * 3 + 1, s2 = l * 3 + 2;
    if (l == 0)
      agg_k<0><<<gridN4, 256, 0, stream>>>(x, nullptr, nullptr, nullptr,
                                           nullptr, nullptr, nullptr, invN,
                                           row_start, csr, Z, N);
    else {
      int p1 = (l - 1) * 3 + 1, p2 = (l - 1) * 3 + 2;
      agg_k<1><<<gridN4, 256, 0, stream>>>(TB,
                                           accum + p1 * 256, g_apply + (l - 1) * HID, b_apply + (l - 1) * HID,
                                           accum + p2 * 256, g_out + (l - 1) * HID, b_out + (l - 1) * HID,
                                           invN, row_start, csr, Z, N);
    }
    gemm_k<0><<<gridG, 256, 0, stream>>>(Z, nullptr, nullptr, nullptr, invN,
                                         Wb + (size_t)l * 16384, TA, accum + s0 * 256, N);
    gemm_k<1><<<gridG, 256, 0, stream>>>(TA, accum + s0 * 256, g_mlp + l * HID, b_mlp + l * HID, invN,
                                         Wb + (size_t)(3 + l) * 16384, TB, accum + s1 * 256, N);
    if (l < 2)
      stats1_k<<<512, 256, 0, stream>>>(TB, accum + s1 * 256, g_apply + l * HID, b_apply + l * HID,
                                        invN, accum + s2 * 256, N);
  }
  int gridP = (2 * P + 127) / 128;
  pred_k<<<gridP, 256, 0, stream>>>(TB, accum + 7 * 256, g_apply + 2 * HID, b_apply + 2 * HID, invN,
                                    ps, pd, ns, nd,
                                    Wb + (size_t)6 * 16384, pb1,
                                    Wb + (size_t)7 * 16384, pb2,
                                    pW3, pb3, out, P);
}

// Round 7
// 929.083 us; speedup vs baseline: 5.0241x; 1.1284x over previous
//
#include <hip/hip_runtime.h>

#define HID 128
#define BN_EPS 1e-5f

typedef __bf16 bf16;
typedef __attribute__((ext_vector_type(8))) __bf16 bf16x8;
typedef __attribute__((ext_vector_type(2))) __bf16 bf16x2;
typedef __attribute__((ext_vector_type(4))) float f32x4;

__device__ __forceinline__ float bnrelu(float x, float a, float c) {
  return fmaxf(fmaf(a, x, c), 0.f);
}

// ---------------- per-node histogram ----------------
__global__ void hist_k(const int* __restrict__ dst, int* __restrict__ cnt, int E) {
  int i = blockIdx.x * blockDim.x + threadIdx.x;
  if (i < E) atomicAdd(&cnt[dst[i]], 1);
}

// block partial sums (1024 elems / block)
__global__ __launch_bounds__(256)
void scan1_k(const int* __restrict__ cnt, int* __restrict__ bsum, int Nn) {
  __shared__ int red[4];
  int tid = threadIdx.x;
  int base = blockIdx.x * 1024;
  int s = 0;
#pragma unroll
  for (int u = 0; u < 4; ++u) {
    int i = base + u * 256 + tid;
    if (i < Nn) s += cnt[i];
  }
#pragma unroll
  for (int d = 1; d < 64; d <<= 1) s += __shfl_xor(s, d, 64);
  int lane = tid & 63, wv = tid >> 6;
  if (lane == 0) red[wv] = s;
  __syncthreads();
  if (tid == 0) bsum[blockIdx.x] = red[0] + red[1] + red[2] + red[3];
}

// exclusive scan of block sums, in place (single wave)
__global__ void scan2_k(int* __restrict__ bsum, int G) {
  int lane = threadIdx.x;
  int carry = 0;
  for (int base = 0; base < G; base += 64) {
    int i = base + lane;
    int v = (i < G) ? bsum[i] : 0;
    int x = v;
#pragma unroll
    for (int d = 1; d < 64; d <<= 1) { int t = __shfl_up(x, d, 64); if (lane >= d) x += t; }
    if (i < G) bsum[i] = carry + x - v;
    carry += __shfl(x, 63, 64);
  }
}

// final scan: row_start
__global__ __launch_bounds__(256)
void scan3_k(const int* __restrict__ cnt, const int* __restrict__ boff,
             int* __restrict__ row_start, int Nn, int E) {
  __shared__ int wtot[4];
  int tid = threadIdx.x, lane = tid & 63, wv = tid >> 6;
  int i0 = blockIdx.x * 1024 + tid * 4;
  int t0 = 0, t1 = 0, t2 = 0, t3 = 0;
  if (i0 + 3 < Nn) {
    int4 v = *(const int4*)(cnt + i0);
    t0 = v.x; t1 = v.y; t2 = v.z; t3 = v.w;
  } else {
    if (i0     < Nn) t0 = cnt[i0];
    if (i0 + 1 < Nn) t1 = cnt[i0 + 1];
    if (i0 + 2 < Nn) t2 = cnt[i0 + 2];
    if (i0 + 3 < Nn) t3 = cnt[i0 + 3];
  }
  int tsum = t0 + t1 + t2 + t3;
  int x = tsum;
#pragma unroll
  for (int d = 1; d < 64; d <<= 1) { int t = __shfl_up(x, d, 64); if (lane >= d) x += t; }
  if (lane == 63) wtot[wv] = x;
  __syncthreads();
  int wo = 0;
  for (int k = 0; k < wv; ++k) wo += wtot[k];
  int base = boff[blockIdx.x] + wo + x - tsum;
  if (i0     < Nn) row_start[i0] = base;
  if (i0 + 1 < Nn) row_start[i0 + 1] = base + t0;
  if (i0 + 2 < Nn) row_start[i0 + 2] = base + t0 + t1;
  if (i0 + 3 < Nn) row_start[i0 + 3] = base + t0 + t1 + t2;
  if (blockIdx.x == 0 && tid == 0) row_start[Nn] = E;
}

// ---------------- coarse-bucket cursor init (bucket = 2048 nodes) ----------------
__global__ void init64_k(const int* __restrict__ row_start, int* __restrict__ bcur64,
                         int Nn, int NB2) {
  int i = threadIdx.x;
  if (i < NB2) {
    int n = i << 11; if (n > Nn) n = Nn;
    bcur64[i] = row_start[n];
  }
}

// ---------------- partition edges into 2048-node buckets, packed (dl<<17)|src ----------------
__global__ __launch_bounds__(256)
void part64_k(const int* __restrict__ src, const int* __restrict__ dst,
              int* __restrict__ bcur64, unsigned* __restrict__ ebuf2, int E) {
  __shared__ int lcnt[64], gbase[64], lcur[64];
  int tid = threadIdx.x;
  if (tid < 64) { lcnt[tid] = 0; lcur[tid] = 0; }
  __syncthreads();
  int base = blockIdx.x * 2048;
  int ok[8]; unsigned pk[8]; int bk[8];
#pragma unroll
  for (int u = 0; u < 8; ++u) {
    int e = base + u * 256 + tid;
    if (e < E) {
      int s = src[e], d = dst[e];
      ok[u] = 1; bk[u] = d >> 11;
      pk[u] = ((unsigned)(d & 2047) << 17) | (unsigned)s;
      atomicAdd(&lcnt[bk[u]], 1);
    } else ok[u] = 0;
  }
  __syncthreads();
  if (tid < 64 && lcnt[tid]) gbase[tid] = atomicAdd(&bcur64[tid], lcnt[tid]);
  __syncthreads();
#pragma unroll
  for (int u = 0; u < 8; ++u) if (ok[u]) {
    int sl = atomicAdd(&lcur[bk[u]], 1);
    ebuf2[gbase[bk[u]] + sl] = pk[u];
  }
}

// ---------------- bucket -> CSR (one block owns one 2048-node bucket) ----------------
__global__ __launch_bounds__(1024)
void fill2_k(const unsigned* __restrict__ ebuf2, const int* __restrict__ row_start,
             int* __restrict__ csr, int Nn) {
  __shared__ int ncur[2048];
  int tid = threadIdx.x;
  ncur[tid] = 0; ncur[tid + 1024] = 0;
  __syncthreads();
  int nb0 = blockIdx.x << 11;
  int hi = nb0 + 2048; if (hi > Nn) hi = Nn;
  int beg = row_start[nb0], end = row_start[hi];
  for (int e = beg + tid; e < end; e += 1024) {
    unsigned v = ebuf2[e];
    int dl = v >> 17, s = (int)(v & 0x1FFFF);
    int p = atomicAdd(&ncur[dl], 1);
    csr[row_start[nb0 + dl] + p] = s;
  }
}

// ---------------- weight convert to bf16 ----------------
__global__ __launch_bounds__(256)
void wconv_k(const float* __restrict__ W0, const float* __restrict__ W1,
             const float* __restrict__ pW1, const float* __restrict__ pW2,
             bf16* __restrict__ Wb) {
  int idx = (blockIdx.x * 256 + threadIdx.x) * 4;
  int seg = idx >> 14, loc = idx & 16383;
  const float* srcp = seg < 3 ? W0 + (size_t)seg * 16384
                    : seg < 6 ? W1 + (size_t)(seg - 3) * 16384
                    : seg == 6 ? pW1 : pW2;
  float4 v = *(const float4*)(srcp + loc);
  union { bf16 h[4]; unsigned long long u; } pk;
  pk.h[0] = (bf16)v.x; pk.h[1] = (bf16)v.y; pk.h[2] = (bf16)v.z; pk.h[3] = (bf16)v.w;
  *(unsigned long long*)(Wb + idx) = pk.u;
}

// ---------------- x -> bf16 convert ----------------
__global__ __launch_bounds__(256)
void xconv_k(const float* __restrict__ X, bf16* __restrict__ Xh, int total) {
  int idx = (blockIdx.x * 256 + threadIdx.x) * 4;
  if (idx >= total) return;
  float4 v = *(const float4*)(X + idx);
  union { bf16 h[4]; unsigned long long u; } pk;
  pk.h[0] = (bf16)v.x; pk.h[1] = (bf16)v.y; pk.h[2] = (bf16)v.z; pk.h[3] = (bf16)v.w;
  *(unsigned long long*)(Xh + idx) = pk.u;
}

// ---------------- aggregation from bf16 source, unroll-8 ----------------
// MODE 0: h = Hh raw.  MODE 1: h = relu(a*Hh+c), coefs from accum slot (outer BN)
template<int MODE>
__global__ __launch_bounds__(256)
void agg_k(const bf16* __restrict__ Hh,
           const float* __restrict__ ac, const float* __restrict__ g, const float* __restrict__ b,
           float invN,
           const int* __restrict__ row_start, const int* __restrict__ csr,
           bf16* __restrict__ Z, int Nn) {
  __shared__ float sA[128], sC[128];
  int tid = threadIdx.x;
  if (MODE) {
    if (tid < 128) {
      float mu = ac[tid] * invN;
      float var = fmaxf(ac[128 + tid] * invN - mu * mu, 0.f);
      float a = g[tid] * rsqrtf(var + BN_EPS);
      sA[tid] = a; sC[tid] = fmaf(-a, mu, b[tid]);
    }
    __syncthreads();
  }
  int wv = tid >> 6, lane = tid & 63;
  int n = blockIdx.x * 4 + wv;
  if (n >= Nn) return;
  int c0 = lane * 2;
  float Ax = 0, Ay = 0, Cx = 0, Cy = 0;
  if (MODE) { Ax = sA[c0]; Ay = sA[c0 + 1]; Cx = sC[c0]; Cy = sC[c0 + 1]; }
  int beg = row_start[n], end = row_start[n + 1];
  bf16x2 hn = *(const bf16x2*)(Hh + (size_t)n * HID + c0);
  float inv = 1.f / fmaxf((float)(end - beg), 1.f);
  float ax0 = 0, ay0 = 0, ax1 = 0, ay1 = 0, ax2 = 0, ay2 = 0, ax3 = 0, ay3 = 0;
  int j = beg;
  for (; j + 8 <= end; j += 8) {
    int s0 = csr[j], s1 = csr[j + 1], s2 = csr[j + 2], s3 = csr[j + 3];
    int s4 = csr[j + 4], s5 = csr[j + 5], s6 = csr[j + 6], s7 = csr[j + 7];
    bf16x2 v0 = *(const bf16x2*)(Hh + (size_t)s0 * HID + c0);
    bf16x2 v1 = *(const bf16x2*)(Hh + (size_t)s1 * HID + c0);
    bf16x2 v2 = *(const bf16x2*)(Hh + (size_t)s2 * HID + c0);
    bf16x2 v3 = *(const bf16x2*)(Hh + (size_t)s3 * HID + c0);
    bf16x2 v4 = *(const bf16x2*)(Hh + (size_t)s4 * HID + c0);
    bf16x2 v5 = *(const bf16x2*)(Hh + (size_t)s5 * HID + c0);
    bf16x2 v6 = *(const bf16x2*)(Hh + (size_t)s6 * HID + c0);
    bf16x2 v7 = *(const bf16x2*)(Hh + (size_t)s7 * HID + c0);
    float x0 = (float)v0[0], y0 = (float)v0[1], x1 = (float)v1[0], y1 = (float)v1[1];
    float x2 = (float)v2[0], y2 = (float)v2[1], x3 = (float)v3[0], y3 = (float)v3[1];
    float x4 = (float)v4[0], y4 = (float)v4[1], x5 = (float)v5[0], y5 = (float)v5[1];
    float x6 = (float)v6[0], y6 = (float)v6[1], x7 = (float)v7[0], y7 = (float)v7[1];
    if (MODE) {
      x0 = bnrelu(x0, Ax, Cx); y0 = bnrelu(y0, Ay, Cy);
      x1 = bnrelu(x1, Ax, Cx); y1 = bnrelu(y1, Ay, Cy);
      x2 = bnrelu(x2, Ax, Cx); y2 = bnrelu(y2, Ay, Cy);
      x3 = bnrelu(x3, Ax, Cx); y3 = bnrelu(y3, Ay, Cy);
      x4 = bnrelu(x4, Ax, Cx); y4 = bnrelu(y4, Ay, Cy);
      x5 = bnrelu(x5, Ax, Cx); y5 = bnrelu(y5, Ay, Cy);
      x6 = bnrelu(x6, Ax, Cx); y6 = bnrelu(y6, Ay, Cy);
      x7 = bnrelu(x7, Ax, Cx); y7 = bnrelu(y7, Ay, Cy);
    }
    ax0 += x0; ay0 += y0; ax1 += x1; ay1 += y1;
    ax2 += x2; ay2 += y2; ax3 += x3; ay3 += y3;
    ax0 += x4; ay0 += y4; ax1 += x5; ay1 += y5;
    ax2 += x6; ay2 += y6; ax3 += x7; ay3 += y7;
  }
  for (; j < end; ++j) {
    int s = csr[j];
    bf16x2 v = *(const bf16x2*)(Hh + (size_t)s * HID + c0);
    float vx = (float)v[0], vy = (float)v[1];
    if (MODE) { vx = bnrelu(vx, Ax, Cx); vy = bnrelu(vy, Ay, Cy); }
    ax0 += vx; ay0 += vy;
  }
  float ax = (ax0 + ax1) + (ax2 + ax3);
  float ay = (ay0 + ay1) + (ay2 + ay3);
  float hx = (float)hn[0], hy = (float)hn[1];
  if (MODE) { hx = bnrelu(hx, Ax, Cx); hy = bnrelu(hy, Ay, Cy); }
  float zx = hx + ax * inv, zy = hy + ay * inv;
  union { bf16 h[2]; unsigned u; } pk;
  pk.h[0] = (bf16)zx; pk.h[1] = (bf16)zy;
  *(unsigned*)((char*)Z + ((size_t)n * HID + c0) * 2) = pk.u;
}

// ---------------- GEMM: C = A @ W^T, bf16 A and weights, fused column stats ----------------
// AMODE 0: A raw bf16. AMODE 1: A bf16 + relu(a*x+c) transform.
// OUTF 0: write bf16 Cb. OUTF 1: write f32 Cf.
template<int AMODE, int OUTF>
__global__ __launch_bounds__(256)
void gemm_k(const bf16* __restrict__ Asrc,
            const float* __restrict__ acIn, const float* __restrict__ g, const float* __restrict__ b,
            float invN,
            const bf16* __restrict__ Wb, bf16* __restrict__ Cb, float* __restrict__ Cf,
            float* __restrict__ accumOut, int Nrows) {
  __shared__ float sA[128], sC[128], sSum[128], sSq[128];
  int tid = threadIdx.x;
  if (tid < 128) {
    sSum[tid] = 0.f; sSq[tid] = 0.f;
    if (AMODE) {
      float mu = acIn[tid] * invN;
      float var = fmaxf(acIn[128 + tid] * invN - mu * mu, 0.f);
      float a = g[tid] * rsqrtf(var + BN_EPS);
      sA[tid] = a; sC[tid] = fmaf(-a, mu, b[tid]);
    }
  }
  __syncthreads();
  int wv = tid >> 6, lane = tid & 63;
  int lm = lane & 15, lg = lane >> 4;
  int rowbase = blockIdx.x * 128 + wv * 32;
  f32x4 acc[2][8] = {};
#pragma unroll
  for (int kk = 0; kk < 4; ++kk) {
    int kb = kk * 32 + lg * 8;
    bf16x8 af[2];
#pragma unroll
    for (int rt = 0; rt < 2; ++rt) {
      int row = rowbase + rt * 16 + lm; if (row > Nrows - 1) row = Nrows - 1;
      bf16x8 raw = *(const bf16x8*)(Asrc + (size_t)row * HID + kb);
      if (AMODE == 0) {
        af[rt] = raw;
      } else {
        float4 a0 = *(const float4*)(sA + kb), a1 = *(const float4*)(sA + kb + 4);
        float4 q0 = *(const float4*)(sC + kb), q1 = *(const float4*)(sC + kb + 4);
        bf16x8 f;
        f[0] = (bf16)bnrelu((float)raw[0], a0.x, q0.x); f[1] = (bf16)bnrelu((float)raw[1], a0.y, q0.y);
        f[2] = (bf16)bnrelu((float)raw[2], a0.z, q0.z); f[3] = (bf16)bnrelu((float)raw[3], a0.w, q0.w);
        f[4] = (bf16)bnrelu((float)raw[4], a1.x, q1.x); f[5] = (bf16)bnrelu((float)raw[5], a1.y, q1.y);
        f[6] = (bf16)bnrelu((float)raw[6], a1.z, q1.z); f[7] = (bf16)bnrelu((float)raw[7], a1.w, q1.w);
        af[rt] = f;
      }
    }
    bf16x8 bfr[8];
#pragma unroll
    for (int ct = 0; ct < 8; ++ct)
      bfr[ct] = *(const bf16x8*)(Wb + (size_t)(ct * 16 + lm) * HID + kb);
#pragma unroll
    for (int rt = 0; rt < 2; ++rt)
#pragma unroll
      for (int ct = 0; ct < 8; ++ct)
        acc[rt][ct] = __builtin_amdgcn_mfma_f32_16x16x32_bf16(af[rt], bfr[ct], acc[rt][ct], 0, 0, 0);
  }
#pragma unroll
  for (int ct = 0; ct < 8; ++ct) {
    int col = ct * 16 + lm;
    float ps = 0.f, pq = 0.f;
#pragma unroll
    for (int rt = 0; rt < 2; ++rt) {
#pragma unroll
      for (int i = 0; i < 4; ++i) {
        int row = rowbase + rt * 16 + lg * 4 + i;
        if (row < Nrows) {
          float v = acc[rt][ct][i];
          if (OUTF) Cf[(size_t)row * HID + col] = v;
          else      Cb[(size_t)row * HID + col] = (bf16)v;
          ps += v; pq = fmaf(v, v, pq);
        }
      }
    }
    ps += __shfl_xor(ps, 16, 64); ps += __shfl_xor(ps, 32, 64);
    pq += __shfl_xor(pq, 16, 64); pq += __shfl_xor(pq, 32, 64);
    if (lane < 16) { atomicAdd(&sSum[col], ps); atomicAdd(&sSq[col], pq); }
  }
  __syncthreads();
  if (tid < 128) {
    atomicAdd(&accumOut[tid], sSum[tid]);
    atomicAdd(&accumOut[128 + tid], sSq[tid]);
  }
}

// ---------------- stats of y=relu(a*x+c) + write Y bf16 ----------------
__global__ __launch_bounds__(256)
void stats1_k(const float* __restrict__ T, const float* __restrict__ acIn,
              const float* __restrict__ g, const float* __restrict__ b, float invN,
              float* __restrict__ accumOut, bf16* __restrict__ Y, int Nrows) {
  int col = threadIdx.x & 127, half = threadIdx.x >> 7;
  float mu = acIn[col] * invN;
  float var = fmaxf(acIn[128 + col] * invN - mu * mu, 0.f);
  float av = g[col] * rsqrtf(var + BN_EPS);
  float cv = fmaf(-av, mu, b[col]);
  float s = 0.f, sq = 0.f;
  for (int r = blockIdx.x * 2 + half; r < Nrows; r += gridDim.x * 2) {
    float x = T[(size_t)r * HID + col];
    x = fmaxf(fmaf(av, x, cv), 0.f);
    Y[(size_t)r * HID + col] = (bf16)x;
    s += x; sq = fmaf(x, x, sq);
  }
  __shared__ float sb[256], qb[256];
  sb[threadIdx.x] = s; qb[threadIdx.x] = sq;
  __syncthreads();
  if (half == 0) {
    s += sb[threadIdx.x + 128]; sq += qb[threadIdx.x + 128];
    atomicAdd(&accumOut[col], s); atomicAdd(&accumOut[128 + col], sq);
  }
}

// ---------------- fused link predictor ----------------
__global__ __launch_bounds__(256)
void pred_k(const float* __restrict__ T, const float* __restrict__ acIn,
            const float* __restrict__ g, const float* __restrict__ b, float invN,
            const int* __restrict__ ps, const int* __restrict__ pd,
            const int* __restrict__ ns, const int* __restrict__ nd,
            const bf16* __restrict__ W1b, const float* __restrict__ b1p,
            const bf16* __restrict__ W2b, const float* __restrict__ b2p,
            const float* __restrict__ w3, const float* __restrict__ b3,
            float* __restrict__ out, int Pn) {
  __shared__ bf16 At[128 * 128];
  __shared__ float sAp[128], sCp[128];
  int tid = threadIdx.x;
  if (tid < 128) {
    float mu = acIn[tid] * invN;
    float var = fmaxf(acIn[128 + tid] * invN - mu * mu, 0.f);
    float a = g[tid] * rsqrtf(var + BN_EPS);
    sAp[tid] = a; sCp[tid] = fmaf(-a, mu, b[tid]);
  }
  __syncthreads();
  int q0 = blockIdx.x * 128;
  {
    int r = tid >> 1;
    int q = q0 + r;
    int cb = (tid & 1) * 64;
    if (q < 2 * Pn) {
      int s, d;
      if (q < Pn) { s = ps[q]; d = pd[q]; } else { s = ns[q - Pn]; d = nd[q - Pn]; }
      const float* rs_ = T + (size_t)s * HID;
      const float* rd_ = T + (size_t)d * HID;
      for (int c = cb; c < cb + 64; c += 4) {
        float4 xs = *(const float4*)(rs_ + c);
        float4 xd = *(const float4*)(rd_ + c);
        float4 av = *(const float4*)(sAp + c);
        float4 cv = *(const float4*)(sCp + c);
        float t0 = bnrelu(xs.x, av.x, cv.x) * bnrelu(xd.x, av.x, cv.x);
        float t1 = bnrelu(xs.y, av.y, cv.y) * bnrelu(xd.y, av.y, cv.y);
        float t2 = bnrelu(xs.z, av.z, cv.z) * bnrelu(xd.z, av.z, cv.z);
        float t3 = bnrelu(xs.w, av.w, cv.w) * bnrelu(xd.w, av.w, cv.w);
        union { bf16 h[4]; unsigned long long u; } pk;
        pk.h[0] = (bf16)t0; pk.h[1] = (bf16)t1; pk.h[2] = (bf16)t2; pk.h[3] = (bf16)t3;
        unsigned addr = (unsigned)(r * 256 + c * 2);
        addr ^= (unsigned)((r & 7) << 4);
        *(unsigned long long*)((char*)At + addr) = pk.u;
      }
    } else {
      for (int c = cb; c < cb + 64; c += 4) {
        unsigned addr = (unsigned)(r * 256 + c * 2);
        addr ^= (unsigned)((r & 7) << 4);
        *(unsigned long long*)((char*)At + addr) = 0ull;
      }
    }
  }
  __syncthreads();
  int wv = tid >> 6, lane = tid & 63;
  int lm = lane & 15, lg = lane >> 4;
  const f32x4 vzero = {0.f, 0.f, 0.f, 0.f};
  f32x4 acc[2][8];
#pragma unroll
  for (int r = 0; r < 2; ++r) for (int c = 0; c < 8; ++c) acc[r][c] = vzero;
#pragma unroll
  for (int kk = 0; kk < 4; ++kk) {
    bf16x8 af[2];
#pragma unroll
    for (int rt = 0; rt < 2; ++rt) {
      int row = wv * 32 + rt * 16 + lm;
      unsigned addr = (unsigned)(row * 256 + kk * 64 + lg * 16);
      addr ^= (unsigned)((row & 7) << 4);
      af[rt] = *(const bf16x8*)((char*)At + addr);
    }
    bf16x8 bfr[8];
#pragma unroll
    for (int ct = 0; ct < 8; ++ct)
      bfr[ct] = *(const bf16x8*)(W1b + (size_t)(ct * 16 + lm) * HID + kk * 32 + lg * 8);
#pragma unroll
    for (int rt = 0; rt < 2; ++rt)
#pragma unroll
      for (int ct = 0; ct < 8; ++ct)
        acc[rt][ct] = __builtin_amdgcn_mfma_f32_16x16x32_bf16(af[rt], bfr[ct], acc[rt][ct], 0, 0, 0);
  }
  __syncthreads();
#pragma unroll
  for (int rt = 0; rt < 2; ++rt)
#pragma unroll
    for (int ct = 0; ct < 8; ++ct) {
      int col = ct * 16 + lm;
      float bb = b1p[col];
#pragma unroll
      for (int i = 0; i < 4; ++i) {
        int row = wv * 32 + rt * 16 + lg * 4 + i;
        float v = fmaxf(acc[rt][ct][i] + bb, 0.f);
        unsigned addr = (unsigned)(row * 256 + col * 2);
        addr ^= (unsigned)((row & 7) << 4);
        *(bf16*)((char*)At + addr) = (bf16)v;
      }
    }
  __syncthreads();
#pragma unroll
  for (int r = 0; r < 2; ++r) for (int c = 0; c < 8; ++c) acc[r][c] = vzero;
#pragma unroll
  for (int kk = 0; kk < 4; ++kk) {
    bf16x8 af[2];
#pragma unroll
    for (int rt = 0; rt < 2; ++rt) {
      int row = wv * 32 + rt * 16 + lm;
      unsigned addr = (unsigned)(row * 256 + kk * 64 + lg * 16);
      addr ^= (unsigned)((row & 7) << 4);
      af[rt] = *(const bf16x8*)((char*)At + addr);
    }
    bf16x8 bfr[8];
#pragma unroll
    for (int ct = 0; ct < 8; ++ct)
      bfr[ct] = *(const bf16x8*)(W2b + (size_t)(ct * 16 + lm) * HID + kk * 32 + lg * 8);
#pragma unroll
    for (int rt = 0; rt < 2; ++rt)
#pragma unroll
      for (int ct = 0; ct < 8; ++ct)
        acc[rt][ct] = __builtin_amdgcn_mfma_f32_16x16x32_bf16(af[rt], bfr[ct], acc[rt][ct], 0, 0, 0);
  }
  float b2v[8], w3v[8];
#pragma unroll
  for (int ct = 0; ct < 8; ++ct) { b2v[ct] = b2p[ct * 16 + lm]; w3v[ct] = w3[ct * 16 + lm]; }
  float b3s = b3[0];
#pragma unroll
  for (int rt = 0; rt < 2; ++rt) {
#pragma unroll
    for (int i = 0; i < 4; ++i) {
      float p = 0.f;
#pragma unroll
      for (int ct = 0; ct < 8; ++ct)
        p += fmaxf(acc[rt][ct][i] + b2v[ct], 0.f) * w3v[ct];
      p += __shfl_xor(p, 1); p += __shfl_xor(p, 2);
      p += __shfl_xor(p, 4); p += __shfl_xor(p, 8);
      int row = wv * 32 + rt * 16 + lg * 4 + i;
      int q = q0 + row;
      if (lm == 0 && q < 2 * Pn) out[q] = p + b3s;
    }
  }
}

// ---------------- launcher ----------------
extern "C" void kernel_launch(void* const* d_in, const int* in_sizes, int n_in,
                              void* d_out, int out_size, void* d_ws, size_t ws_size,
                              hipStream_t stream) {
  const float* x  = (const float*)d_in[0];
  const int* src  = (const int*)d_in[1];
  const int* dst  = (const int*)d_in[2];
  const int* ps   = (const int*)d_in[3];
  const int* pd   = (const int*)d_in[4];
  const int* ns   = (const int*)d_in[5];
  const int* nd   = (const int*)d_in[6];
  const float* W0 = (const float*)d_in[7];
  const float* W1 = (const float*)d_in[8];
  const float* g_mlp   = (const float*)d_in[9];
  const float* b_mlp   = (const float*)d_in[10];
  const float* g_apply = (const float*)d_in[11];
  const float* b_apply = (const float*)d_in[12];
  const float* g_out   = (const float*)d_in[13];
  const float* b_out   = (const float*)d_in[14];
  const float* pW1 = (const float*)d_in[15];
  const float* pb1 = (const float*)d_in[16];
  const float* pW2 = (const float*)d_in[17];
  const float* pb2 = (const float*)d_in[18];
  const float* pW3 = (const float*)d_in[19];
  const float* pb3 = (const float*)d_in[20];
  float* out = (float*)d_out;

  const int N = in_sizes[0] / HID;
  const int E = in_sizes[1];
  const int P = in_sizes[3];
  const int NB2 = (N + 2047) >> 11;

  char* w = (char*)d_ws;
  size_t off = 0;
  auto alloc = [&](size_t bytes) -> void* {
    void* p = w + off;
    off = (off + bytes + 255) & ~(size_t)255;
    return p;
  };
  bf16*  Z   = (bf16*)alloc((size_t)N * HID * 2);
  bf16*  TAb = (bf16*)alloc((size_t)N * HID * 2);
  float* TB  = (float*)alloc((size_t)N * HID * 4);
  bf16*  Yb  = (bf16*)alloc((size_t)N * HID * 2);
  bf16*  Xh  = (bf16*)alloc((size_t)N * HID * 2);
  int*   csr = (int*)alloc((size_t)E * 4);
  unsigned* ebuf2 = (unsigned*)alloc((size_t)E * 4);
  int*   row_start = (int*)alloc((size_t)(N + 1) * 4);
  size_t zoff = off;
  int*   cnt   = (int*)alloc((size_t)N * 4);
  float* accum = (float*)alloc(9 * 256 * 4);
  size_t zbytes = off - zoff;
  int*   bsum   = (int*)alloc(256 * 4);
  int*   bcur64 = (int*)alloc(64 * 4);
  bf16*  Wb = (bf16*)alloc(8 * 16384 * 2);
  (void)ws_size; (void)n_in; (void)out_size;

  const int G = (N + 1023) / 1024;
  const float invN = 1.f / (float)N;

  hipMemsetAsync(w + zoff, 0, zbytes, stream);
  int gridE = (E + 255) / 256;
  hist_k<<<gridE, 256, 0, stream>>>(dst, cnt, E);
  scan1_k<<<G, 256, 0, stream>>>(cnt, bsum, N);
  scan2_k<<<1, 64, 0, stream>>>(bsum, G);
  scan3_k<<<G, 256, 0, stream>>>(cnt, bsum, row_start, N, E);
  init64_k<<<1, 64, 0, stream>>>(row_start, bcur64, N, NB2);
  part64_k<<<(E + 2047) / 2048, 256, 0, stream>>>(src, dst, bcur64, ebuf2, E);
  fill2_k<<<NB2, 1024, 0, stream>>>(ebuf2, row_start, csr, N);
  wconv_k<<<128, 256, 0, stream>>>(W0, W1, pW1, pW2, Wb);
  xconv_k<<<(N * HID / 4 + 255) / 256, 256, 0, stream>>>(x, Xh, N * HID);

  int gridN4 = (N + 3) / 4;
  int gridG  = (N + 127) / 128;

  for (int l = 0; l < 3; ++l) {
    int s0 = l * 3 + 0, s1 = l * 3 + 1, s2 = l * 3 + 2;
    if (l == 0)
      agg_k<0><<<gridN4, 256, 0, stream>>>(Xh, nullptr, nullptr, nullptr, invN,
                                           row_start, csr, Z, N);
    else {
      int p2 = (l - 1) * 3 + 2;
      agg_k<1><<<gridN4, 256, 0, stream>>>(Yb,
                                           accum + p2 * 256, g_out + (l - 1) * HID, b_out + (l - 1) * HID,
                                           invN, row_start, csr, Z, N);
    }
    gemm_k<0, 0><<<gridG, 256, 0, stream>>>(Z, nullptr, nullptr, nullptr, invN,
                                            Wb + (size_t)l * 16384, TAb, nullptr,
                                            accum + s0 * 256, N);
    gemm_k<1, 1><<<gridG, 256, 0, stream>>>(TAb, accum + s0 * 256, g_mlp + l * HID, b_mlp + l * HID,
                                            invN, Wb + (size_t)(3 + l) * 16384, nullptr, TB,
                                            accum + s1 * 256, N);
    if (l < 2)
      stats1_k<<<512, 256, 0, stream>>>(TB, accum + s1 * 256, g_apply + l * HID, b_apply + l * HID,
                                        invN, accum + s2 * 256, Yb, N);
  }
  int gridP = (2 * P + 127) / 128;
  pred_k<<<gridP, 256, 0, stream>>>(TB, accum + 7 * 256, g_apply + 2 * HID, b_apply + 2 * HID, invN,
                                    ps, pd, ns, nd,
                                    Wb + (size_t)6 * 16384, pb1,
                                    Wb + (size_t)7 * 16384, pb2,
                                    pW3, pb3, out, P);
}